// Round 9
// baseline (186.285 us; speedup 1.0000x reference)
//
#include <hip/hip_runtime.h>
#include <hip/hip_bf16.h>
#include <math.h>

#define NTOK 8192
#define DIN  4096
#define HG   256
#define NE   64
#define SPLITK 4
#define KSTEPS 32          // ksteps of 32 per split (4096/4/32)
#define TR   16            // rows per tail block

typedef __attribute__((ext_vector_type(8))) short short8;
typedef __attribute__((ext_vector_type(4))) float f32x4;

__device__ __forceinline__ unsigned short f2bf_rne(float f) {
    union { float f; unsigned int u; } v; v.f = f;
    unsigned int r = v.u + 0x7fffu + ((v.u >> 16) & 1u);
    return (unsigned short)(r >> 16);
}
__device__ __forceinline__ float bf2f(unsigned short b) {
    union { unsigned int u; float f; } v; v.u = ((unsigned int)b) << 16;
    return v.f;
}

typedef const __attribute__((address_space(1))) unsigned int* gptr_t;
typedef __attribute__((address_space(3))) unsigned int* lptr_t;
__device__ __forceinline__ void gload_lds16(const void* g, void* l) {
    __builtin_amdgcn_global_load_lds((gptr_t)g, (lptr_t)l, 16, 0, 0);
}

#define WAIT_VMCNT0 { asm volatile("s_waitcnt vmcnt(0)" ::: "memory"); \
                      __builtin_amdgcn_sched_barrier(0); }
#define WAIT_LGKM0  { asm volatile("s_waitcnt lgkmcnt(0)" ::: "memory"); \
                      __builtin_amdgcn_sched_barrier(0); }

// ---------------------------------------------------------------------------
// Pre-convert w1 [HG][DIN] fp32 -> fragment-ordered bf16 hi/lo tiles.
// w1t[kstep][c][lane][j]: c = hl*16+unit; value = (hi|lo) of
// w1[unit*16 + (lane&15)][kstep*32 + (lane>>4)*8 + j].   (validated r3-r8)
// ---------------------------------------------------------------------------
__global__ __launch_bounds__(512) void convert_w1_kernel(
    const float* __restrict__ w1, unsigned short* __restrict__ w1t)
{
    const int id    = blockIdx.x * 512 + threadIdx.x;
    const int lane  = id & 63;
    const int cg    = id >> 6;           // 0..4095
    const int kstep = cg >> 5;
    const int c     = cg & 31;
    const int hl    = c >> 4;
    const int unit  = c & 15;
    const int n     = unit * 16 + (lane & 15);
    const int k     = kstep * 32 + ((lane >> 4) & 3) * 8;

    const float* src = w1 + (size_t)n * DIN + k;
    short8 v;
#pragma unroll
    for (int j = 0; j < 8; ++j) {
        float f = src[j];
        unsigned short hi = f2bf_rne(f);
        v[j] = (hl == 0) ? (short)hi : (short)f2bf_rne(f - bf2f(hi));
    }
    *(short8*)(w1t + (size_t)cg * 512 + lane * 8) = v;
}

// ---------------------------------------------------------------------------
// GEMM1 (split-K): P[s][NTOK][HG] = x(bf16x3) @ w1^T for k-range s.
// 512 blocks = 128 m-tiles (BM=64) x 4 splitK; 256 thr = 4 waves, each wave
// a 64x64 n-quadrant (48 MFMA : 16 ds_read = 3:1).
// LDS 40 KB (Bs single 32 KB + As single 8 KB) -> 4 blocks/CU = 16 waves/CU:
// TLP covers the per-block load-drain (m114 wave-overlap, r6 evidence).
// Schedule: x(tt+1) issued at TOP of kstep (flies across MFMA); barrier#1
// with lgkmcnt(0) only (x loads stay in flight); B gloads + CVT/ds_write;
// vmcnt(0) drain (L2-resident w1t) ; barrier#2.
// ---------------------------------------------------------------------------
__global__ __launch_bounds__(256, 4) void gemm1_mfma_kernel(
    const float* __restrict__ x, const unsigned short* __restrict__ w1t,
    float* __restrict__ P)
{
    __shared__ unsigned short As[2][4][512];    // [hl][unit][q*8+j] : 8 KB
    __shared__ unsigned short Bs[2][16][512];   // [hl][unit][...]   : 32 KB

    const int bid  = blockIdx.x;
    const int mblk = bid & 127;
    const int s    = bid >> 7;     // blocks sharing x-rows land on same XCD (128%8==0)
    const int t    = threadIdx.x;
    const int lane = t & 63;
    const int w    = t >> 6;       // wave = n-quadrant 0..3

    const int m_base = mblk * 64;
    const int kstep0 = s * KSTEPS;

    // A staging: thread t -> unit=t>>6, q=t&63: row=unit*16+(q&15),
    // k-off=(q>>4)*8; 8 contiguous floats; lane-contiguous LDS writes.
    const int a_unit = t >> 6;
    const int a_q    = t & 63;
    const int a_row  = a_unit * 16 + (a_q & 15);
    const int a_koff = (a_q >> 4) * 8;
    const float* asrc = x + (size_t)(m_base + a_row) * DIN
                          + (size_t)kstep0 * 32 + a_koff;
    const int a_ldso = a_q * 8;

    f32x4 acc[4][4];
#pragma unroll
    for (int i = 0; i < 4; ++i)
#pragma unroll
        for (int j = 0; j < 4; ++j) acc[i][j] = (f32x4)0.f;

#define CVT8_STORE(F0, F1)                                                    \
    {   short8 vh_, vl_;                                                      \
        float ff_[8] = { (F0).x, (F0).y, (F0).z, (F0).w,                      \
                         (F1).x, (F1).y, (F1).z, (F1).w };                    \
        _Pragma("unroll")                                                     \
        for (int j_ = 0; j_ < 8; ++j_) {                                      \
            unsigned short h_ = f2bf_rne(ff_[j_]);                            \
            vh_[j_] = (short)h_;                                              \
            vl_[j_] = (short)f2bf_rne(ff_[j_] - bf2f(h_));                    \
        }                                                                     \
        *(short8*)&As[0][a_unit][a_ldso] = vh_;                               \
        *(short8*)&As[1][a_unit][a_ldso] = vl_;                               \
    }

#define ISSUE_B(KS)                                                           \
    _Pragma("unroll")                                                         \
    for (int i_ = 0; i_ < 8; ++i_) {                                          \
        const int c_ = w * 8 + i_;                                            \
        gload_lds16(w1t + ((size_t)(KS) * 32 + c_) * 512 + lane * 8,          \
                    &Bs[c_ >> 4][c_ & 15][0]);                                \
    }

    // ---- prologue: B(0) gloads + x(0) CVT -> As; full drain; barrier ----
    {
        float4 a0 = *(const float4*)(asrc);
        float4 a1 = *(const float4*)(asrc + 4);
        ISSUE_B(kstep0)
        CVT8_STORE(a0, a1)
        WAIT_VMCNT0
        WAIT_LGKM0
        __builtin_amdgcn_s_barrier();
    }

    // ---- main loop ----
#pragma unroll 1
    for (int tt = 0; tt < KSTEPS; ++tt) {
        const bool has1 = (tt + 1 < KSTEPS);

        // issue x(tt+1) reg loads FIRST: they fly across the MFMA phase
        float4 nx0, nx1;
        if (has1) {
            const float* ap = asrc + (size_t)(tt + 1) * 32;
            nx0 = *(const float4*)(ap);
            nx1 = *(const float4*)(ap + 4);
        }

        // fragments (lane*16B contiguous -> conflict-free)
        short8 ahf[4], alf[4], bhf[4], blf[4];
#pragma unroll
        for (int mr = 0; mr < 4; ++mr) {
            ahf[mr] = *(const short8*)&As[0][mr][lane * 8];
            alf[mr] = *(const short8*)&As[1][mr][lane * 8];
        }
#pragma unroll
        for (int nr = 0; nr < 4; ++nr) {
            bhf[nr] = *(const short8*)&Bs[0][w * 4 + nr][lane * 8];
            blf[nr] = *(const short8*)&Bs[1][w * 4 + nr][lane * 8];
        }

        // bf16x3: Ah*Bh + Ah*Bl + Al*Bh   (48 MFMA)
        __builtin_amdgcn_s_setprio(1);
#pragma unroll
        for (int mr = 0; mr < 4; ++mr)
#pragma unroll
            for (int nr = 0; nr < 4; ++nr)
                acc[mr][nr] = __builtin_amdgcn_mfma_f32_16x16x32_bf16(
                    ahf[mr], bhf[nr], acc[mr][nr], 0, 0, 0);
#pragma unroll
        for (int mr = 0; mr < 4; ++mr)
#pragma unroll
            for (int nr = 0; nr < 4; ++nr)
                acc[mr][nr] = __builtin_amdgcn_mfma_f32_16x16x32_bf16(
                    ahf[mr], blf[nr], acc[mr][nr], 0, 0, 0);
#pragma unroll
        for (int mr = 0; mr < 4; ++mr)
#pragma unroll
            for (int nr = 0; nr < 4; ++nr)
                acc[mr][nr] = __builtin_amdgcn_mfma_f32_16x16x32_bf16(
                    alf[mr], bhf[nr], acc[mr][nr], 0, 0, 0);
        __builtin_amdgcn_s_setprio(0);

        if (has1) {
            // barrier #1: everyone done READING As/Bs (ds data already
            // delivered to regs; no vmcnt drain -> x loads stay in flight)
            WAIT_LGKM0
            __builtin_amdgcn_s_barrier();

            ISSUE_B(kstep0 + tt + 1)     // refill Bs (single buffer)
            CVT8_STORE(nx0, nx1)         // compiler waits x only (vmcnt(8))

            WAIT_VMCNT0                  // B gloads landed (L2, short)
            WAIT_LGKM0                   // As ds_writes visible
            __builtin_amdgcn_s_barrier();// barrier #2: tile tt+1 ready
        }
    }
#undef ISSUE_B
#undef CVT8_STORE

    // ---- epilogue: store fp32 partial (mapping validated r3-r8) ----
    float* pb = P + (size_t)s * ((size_t)NTOK * HG);
#pragma unroll
    for (int mr = 0; mr < 4; ++mr)
#pragma unroll
        for (int nr = 0; nr < 4; ++nr) {
            const int n = w * 64 + nr * 16 + (lane & 15);
#pragma unroll
            for (int r = 0; r < 4; ++r) {
                const int m = m_base + mr * 16 + ((lane >> 4) & 3) * 4 + r;
                pb[(size_t)m * HG + n] = acc[mr][nr][r];
            }
        }
}

// ---------------------------------------------------------------------------
// Fused tail: 512 blocks x 512 thr, TR=16 rows/block, 25 KB LDS ->
// 2 blocks/CU. (unchanged from r6-r8 -- validated, ~4 us)
// d_out = [ indices(float) N*2 | gates N*2 | probs N*64 ]
// ---------------------------------------------------------------------------
__global__ __launch_bounds__(512, 4) void reduce_gate_kernel(
    const float* __restrict__ P, const float* __restrict__ b1,
    const float* __restrict__ w2, float* __restrict__ out)
{
    __shared__ float h_lds[TR][260];
    __shared__ float lg[NE][33];

    const int t    = threadIdx.x;
    const int lane = t & 63;
    const int w    = t >> 6;
    const int r0   = blockIdx.x * TR;
    const size_t SS = (size_t)NTOK * HG;

    // ---- phase 1: reduce + bias + gelu (coalesced: 32 thr = one row) ----
    {
        const int row = t >> 5;          // 0..15
        const int sg  = t & 31;          // 8 floats at cols sg*8
        const size_t base = (size_t)(r0 + row) * HG + sg * 8;

        float q[8];
#pragma unroll
        for (int half = 0; half < 2; ++half) {
            float4 v0 = *(const float4*)(P + base + half * 4);
            float4 v1 = *(const float4*)(P + base + SS + half * 4);
            float4 v2 = *(const float4*)(P + base + 2 * SS + half * 4);
            float4 v3 = *(const float4*)(P + base + 3 * SS + half * 4);
            float4 bb = *(const float4*)(b1 + sg * 8 + half * 4);
            q[half * 4 + 0] = v0.x + v1.x + v2.x + v3.x + bb.x;
            q[half * 4 + 1] = v0.y + v1.y + v2.y + v3.y + bb.y;
            q[half * 4 + 2] = v0.z + v1.z + v2.z + v3.z + bb.z;
            q[half * 4 + 3] = v0.w + v1.w + v2.w + v3.w + bb.w;
        }
#pragma unroll
        for (int c = 0; c < 8; ++c)
            q[c] = 0.5f * q[c] * (1.0f + erff(q[c] * 0.70710678118654752440f));

        *(float4*)&h_lds[row][sg * 8]     = make_float4(q[0], q[1], q[2], q[3]);
        *(float4*)&h_lds[row][sg * 8 + 4] = make_float4(q[4], q[5], q[6], q[7]);
    }
    __syncthreads();

    // ---- phase 2: logits; wave w -> 8 experts, quarter-K per lane ----
    const int e0   = w * 8;
    const int rowp = lane & 15;
    const int kq   = lane >> 4;          // 0..3 -> k-range kq*64

    float acc[8];
#pragma unroll
    for (int i = 0; i < 8; ++i) acc[i] = 0.f;

    const float* w2b = w2 + (size_t)e0 * HG + kq * 64;
#pragma unroll 1
    for (int kc = 0; kc < 64; kc += 8) {
        float a[8];
        *(float4*)&a[0] = *(const float4*)&h_lds[rowp][kq * 64 + kc];
        *(float4*)&a[4] = *(const float4*)&h_lds[rowp][kq * 64 + kc + 4];
#pragma unroll
        for (int n = 0; n < 8; ++n) {
            const float* wr = w2b + (size_t)n * HG + kc;
            float4 w0 = *(const float4*)(wr);
            float4 w1v = *(const float4*)(wr + 4);
            acc[n] = fmaf(w0.x, a[0], acc[n]);
            acc[n] = fmaf(w0.y, a[1], acc[n]);
            acc[n] = fmaf(w0.z, a[2], acc[n]);
            acc[n] = fmaf(w0.w, a[3], acc[n]);
            acc[n] = fmaf(w1v.x, a[4], acc[n]);
            acc[n] = fmaf(w1v.y, a[5], acc[n]);
            acc[n] = fmaf(w1v.z, a[6], acc[n]);
            acc[n] = fmaf(w1v.w, a[7], acc[n]);
        }
    }
#pragma unroll
    for (int n = 0; n < 8; ++n) {
        acc[n] += __shfl_xor(acc[n], 16);
        acc[n] += __shfl_xor(acc[n], 32);
    }
    if (lane < 16) {
#pragma unroll
        for (int n = 0; n < 8; ++n) lg[e0 + n][rowp] = acc[n];
    }
    __syncthreads();

    // ---- phase 3: softmax + stable top-2 (threads 0..15) ----
    if (t < TR) {
        float l[NE];
#pragma unroll
        for (int e = 0; e < NE; ++e) l[e] = lg[e][t];

        float mx = l[0];
#pragma unroll
        for (int e = 1; e < NE; ++e) mx = fmaxf(mx, l[e]);

        float ssum = 0.f;
#pragma unroll
        for (int e = 0; e < NE; ++e) { float p = expf(l[e] - mx); l[e] = p; ssum += p; }
        const float inv = 1.0f / ssum;
#pragma unroll
        for (int e = 0; e < NE; ++e) l[e] *= inv;

        float v1 = -1.0f, v2 = -2.0f;
        int   i1 = 0,     i2 = 0;
#pragma unroll
        for (int e = 0; e < NE; ++e) {
            const float p  = l[e];
            const bool  g1 = p > v1;
            const bool  g2 = p > v2;
            const float nv2 = g1 ? v1 : (g2 ? p : v2);
            const int   ni2 = g1 ? i1 : (g2 ? e : i2);
            v1 = g1 ? p : v1;
            i1 = g1 ? e : i1;
            v2 = nv2;
            i2 = ni2;
        }

        const int row = r0 + t;
        float* out_idx  = out;
        float* out_gate = out + 2 * NTOK;
        float* out_prob = out + 4 * NTOK;
        out_idx[2 * row + 0]  = (float)i1;
        out_idx[2 * row + 1]  = (float)i2;
        out_gate[2 * row + 0] = v1;
        out_gate[2 * row + 1] = v2;

        float* pr = out_prob + (size_t)row * NE;
#pragma unroll
        for (int e = 0; e < NE; e += 4)
            *(float4*)(pr + e) = make_float4(l[e], l[e + 1], l[e + 2], l[e + 3]);
    }
}

extern "C" void kernel_launch(void* const* d_in, const int* in_sizes, int n_in,
                              void* d_out, int out_size, void* d_ws, size_t ws_size,
                              hipStream_t stream) {
    const float* x  = (const float*)d_in[0];
    const float* w1 = (const float*)d_in[1];
    const float* b1 = (const float*)d_in[2];
    const float* w2 = (const float*)d_in[3];
    float* out = (float*)d_out;

    // workspace: w1t (4 MB) | P (32 MB)  = 36 MB
    unsigned short* w1t = (unsigned short*)d_ws;
    float* P = (float*)((char*)d_ws + (4u << 20));

    convert_w1_kernel<<<512, 512, 0, stream>>>(w1, w1t);
    gemm1_mfma_kernel<<<512, 256, 0, stream>>>(x, w1t, P);
    reduce_gate_kernel<<<512, 512, 0, stream>>>(P, b1, w2, out);
}

// Round 10
// 127.480 us; speedup vs baseline: 1.4613x; 1.4613x over previous
//
#include <hip/hip_runtime.h>
#include <hip/hip_bf16.h>
#include <math.h>

#define NTOK 8192
#define DIN  4096
#define HG   256
#define NE   64
#define SPLITK 4
#define KSTEPS 32          // ksteps of 32 per split (4096/4/32)
#define TR   16            // rows per tail block

typedef __attribute__((ext_vector_type(8))) short short8;
typedef __attribute__((ext_vector_type(4))) float f32x4;

__device__ __forceinline__ unsigned short f2bf_rne(float f) {
    union { float f; unsigned int u; } v; v.f = f;
    unsigned int r = v.u + 0x7fffu + ((v.u >> 16) & 1u);
    return (unsigned short)(r >> 16);
}
__device__ __forceinline__ float bf2f(unsigned short b) {
    union { unsigned int u; float f; } v; v.u = ((unsigned int)b) << 16;
    return v.f;
}

// ---------------------------------------------------------------------------
// Pre-convert w1 [HG][DIN] fp32 -> fragment-ordered bf16 hi/lo tiles.
// w1t[kstep][c][lane][j]: c = hl*16+unit; value = (hi|lo) of
// w1[unit*16 + (lane&15)][kstep*32 + (lane>>4)*8 + j].   (validated r3-r9)
// ---------------------------------------------------------------------------
__global__ __launch_bounds__(512) void convert_w1_kernel(
    const float* __restrict__ w1, unsigned short* __restrict__ w1t)
{
    const int id    = blockIdx.x * 512 + threadIdx.x;
    const int lane  = id & 63;
    const int cg    = id >> 6;           // 0..4095
    const int kstep = cg >> 5;
    const int c     = cg & 31;
    const int hl    = c >> 4;
    const int unit  = c & 15;
    const int n     = unit * 16 + (lane & 15);
    const int k     = kstep * 32 + ((lane >> 4) & 3) * 8;

    const float* src = w1 + (size_t)n * DIN + k;
    short8 v;
#pragma unroll
    for (int j = 0; j < 8; ++j) {
        float f = src[j];
        unsigned short hi = f2bf_rne(f);
        v[j] = (hl == 0) ? (short)hi : (short)f2bf_rne(f - bf2f(hi));
    }
    *(short8*)(w1t + (size_t)cg * 512 + lane * 8) = v;
}

// ---------------------------------------------------------------------------
// GEMM1 (split-K), ZERO-LDS dataflow design:
// P[s][NTOK][HG] = x(bf16x3) @ w1^T for k-range s.
// 512 blocks = 128 m-tiles (BM=64) x 4 splitK; 512 thr = 8 waves (2M x 4N of
// 32x64 wave tiles). NO LDS, NO BARRIERS:
//  - B fragments load DIRECTLY from pre-tiled w1t (L2-resident 4 MB) --
//    one coalesced dwordx4 per lane, already in MFMA fragment order.
//  - A fragments load directly from x in fragment order (16 rows x 128 B
//    contiguous per wave-load); 4 n-waves share rows -> L1 dedup; each wave
//    converts its own A to bf16 hi/lo in registers (VALU co-issues w/ MFMA).
// 16 waves/CU (VGPR<=128 via launch_bounds) -> latency self-hiding, no
// lockstep. Math/layouts/epilogue identical to validated r5-r9 kernels.
// ---------------------------------------------------------------------------
__global__ __launch_bounds__(512, 4) void gemm1_mfma_kernel(
    const float* __restrict__ x, const unsigned short* __restrict__ w1t,
    float* __restrict__ P)
{
    const int bid  = blockIdx.x;
    const int mblk = bid & 127;
    const int s    = bid >> 7;
    const int t    = threadIdx.x;
    const int lane = t & 63;
    const int w    = t >> 6;          // 0..7
    const int wm   = w >> 2;          // 0..1
    const int wn   = w & 3;           // 0..3

    const int m_base = mblk * 64;
    const int kstep0 = s * KSTEPS;

    // A per-lane addressing (fragment order, validated layout):
    // frag mr: row = m_base + wm*32 + mr*16 + (lane&15), k-off = (lane>>4)*8
    const float* a0 = x + (size_t)(m_base + wm * 32 + (lane & 15)) * DIN
                        + (size_t)kstep0 * 32 + ((lane >> 4) * 8);
    const float* a1 = a0 + 16 * DIN;

    // B per-lane addressing: chunk c at w1t[(kstep*32 + c)*512 + lane*8]
    const unsigned short* bbase = w1t + ((size_t)kstep0 * 32) * 512 + lane * 8;

    f32x4 acc[2][4];
#pragma unroll
    for (int i = 0; i < 2; ++i)
#pragma unroll
        for (int j = 0; j < 4; ++j) acc[i][j] = (f32x4)0.f;

#pragma unroll 1
    for (int tt = 0; tt < KSTEPS; ++tt) {
        // ---- A loads first (needed earliest, by CVT) ----
        const float* ap0 = a0 + (size_t)tt * 32;
        const float* ap1 = a1 + (size_t)tt * 32;
        float4 f00 = *(const float4*)(ap0);
        float4 f01 = *(const float4*)(ap0 + 4);
        float4 f10 = *(const float4*)(ap1);
        float4 f11 = *(const float4*)(ap1 + 4);

        // ---- B loads (fragment-ready bf16, L2-hit, coalesced) ----
        const unsigned short* bk = bbase + (size_t)tt * 32 * 512;
        short8 bh[4], bl[4];
#pragma unroll
        for (int nr = 0; nr < 4; ++nr) {
            bh[nr] = *(const short8*)(bk + (wn * 4 + nr) * 512);
            bl[nr] = *(const short8*)(bk + (16 + wn * 4 + nr) * 512);
        }

        // ---- CVT A -> bf16 hi/lo in registers ----
        short8 ah[2], al[2];
        {
            float ff0[8] = { f00.x, f00.y, f00.z, f00.w,
                             f01.x, f01.y, f01.z, f01.w };
            float ff1[8] = { f10.x, f10.y, f10.z, f10.w,
                             f11.x, f11.y, f11.z, f11.w };
#pragma unroll
            for (int j = 0; j < 8; ++j) {
                unsigned short h0 = f2bf_rne(ff0[j]);
                ah[0][j] = (short)h0;
                al[0][j] = (short)f2bf_rne(ff0[j] - bf2f(h0));
                unsigned short h1 = f2bf_rne(ff1[j]);
                ah[1][j] = (short)h1;
                al[1][j] = (short)f2bf_rne(ff1[j] - bf2f(h1));
            }
        }

        // ---- bf16x3: Ah*Bh + Ah*Bl + Al*Bh   (24 MFMA) ----
#pragma unroll
        for (int mr = 0; mr < 2; ++mr)
#pragma unroll
            for (int nr = 0; nr < 4; ++nr)
                acc[mr][nr] = __builtin_amdgcn_mfma_f32_16x16x32_bf16(
                    ah[mr], bh[nr], acc[mr][nr], 0, 0, 0);
#pragma unroll
        for (int mr = 0; mr < 2; ++mr)
#pragma unroll
            for (int nr = 0; nr < 4; ++nr)
                acc[mr][nr] = __builtin_amdgcn_mfma_f32_16x16x32_bf16(
                    ah[mr], bl[nr], acc[mr][nr], 0, 0, 0);
#pragma unroll
        for (int mr = 0; mr < 2; ++mr)
#pragma unroll
            for (int nr = 0; nr < 4; ++nr)
                acc[mr][nr] = __builtin_amdgcn_mfma_f32_16x16x32_bf16(
                    al[mr], bh[nr], acc[mr][nr], 0, 0, 0);
    }

    // ---- epilogue: store fp32 partial (mapping validated r5-r9) ----
    float* pb = P + (size_t)s * ((size_t)NTOK * HG);
#pragma unroll
    for (int mr = 0; mr < 2; ++mr)
#pragma unroll
        for (int nr = 0; nr < 4; ++nr) {
            const int n = wn * 64 + nr * 16 + (lane & 15);
#pragma unroll
            for (int r = 0; r < 4; ++r) {
                const int m = m_base + wm * 32 + mr * 16 + ((lane >> 4) & 3) * 4 + r;
                pb[(size_t)m * HG + n] = acc[mr][nr][r];
            }
        }
}

// ---------------------------------------------------------------------------
// Fused tail: 512 blocks x 512 thr, TR=16 rows/block, 25 KB LDS ->
// 2 blocks/CU. (unchanged from r6-r9 -- validated, ~4 us)
// d_out = [ indices(float) N*2 | gates N*2 | probs N*64 ]
// ---------------------------------------------------------------------------
__global__ __launch_bounds__(512, 4) void reduce_gate_kernel(
    const float* __restrict__ P, const float* __restrict__ b1,
    const float* __restrict__ w2, float* __restrict__ out)
{
    __shared__ float h_lds[TR][260];
    __shared__ float lg[NE][33];

    const int t    = threadIdx.x;
    const int lane = t & 63;
    const int w    = t >> 6;
    const int r0   = blockIdx.x * TR;
    const size_t SS = (size_t)NTOK * HG;

    // ---- phase 1: reduce + bias + gelu (coalesced: 32 thr = one row) ----
    {
        const int row = t >> 5;          // 0..15
        const int sg  = t & 31;          // 8 floats at cols sg*8
        const size_t base = (size_t)(r0 + row) * HG + sg * 8;

        float q[8];
#pragma unroll
        for (int half = 0; half < 2; ++half) {
            float4 v0 = *(const float4*)(P + base + half * 4);
            float4 v1 = *(const float4*)(P + base + SS + half * 4);
            float4 v2 = *(const float4*)(P + base + 2 * SS + half * 4);
            float4 v3 = *(const float4*)(P + base + 3 * SS + half * 4);
            float4 bb = *(const float4*)(b1 + sg * 8 + half * 4);
            q[half * 4 + 0] = v0.x + v1.x + v2.x + v3.x + bb.x;
            q[half * 4 + 1] = v0.y + v1.y + v2.y + v3.y + bb.y;
            q[half * 4 + 2] = v0.z + v1.z + v2.z + v3.z + bb.z;
            q[half * 4 + 3] = v0.w + v1.w + v2.w + v3.w + bb.w;
        }
#pragma unroll
        for (int c = 0; c < 8; ++c)
            q[c] = 0.5f * q[c] * (1.0f + erff(q[c] * 0.70710678118654752440f));

        *(float4*)&h_lds[row][sg * 8]     = make_float4(q[0], q[1], q[2], q[3]);
        *(float4*)&h_lds[row][sg * 8 + 4] = make_float4(q[4], q[5], q[6], q[7]);
    }
    __syncthreads();

    // ---- phase 2: logits; wave w -> 8 experts, quarter-K per lane ----
    const int e0   = w * 8;
    const int rowp = lane & 15;
    const int kq   = lane >> 4;          // 0..3 -> k-range kq*64

    float acc[8];
#pragma unroll
    for (int i = 0; i < 8; ++i) acc[i] = 0.f;

    const float* w2b = w2 + (size_t)e0 * HG + kq * 64;
#pragma unroll 1
    for (int kc = 0; kc < 64; kc += 8) {
        float a[8];
        *(float4*)&a[0] = *(const float4*)&h_lds[rowp][kq * 64 + kc];
        *(float4*)&a[4] = *(const float4*)&h_lds[rowp][kq * 64 + kc + 4];
#pragma unroll
        for (int n = 0; n < 8; ++n) {
            const float* wr = w2b + (size_t)n * HG + kc;
            float4 w0 = *(const float4*)(wr);
            float4 w1v = *(const float4*)(wr + 4);
            acc[n] = fmaf(w0.x, a[0], acc[n]);
            acc[n] = fmaf(w0.y, a[1], acc[n]);
            acc[n] = fmaf(w0.z, a[2], acc[n]);
            acc[n] = fmaf(w0.w, a[3], acc[n]);
            acc[n] = fmaf(w1v.x, a[4], acc[n]);
            acc[n] = fmaf(w1v.y, a[5], acc[n]);
            acc[n] = fmaf(w1v.z, a[6], acc[n]);
            acc[n] = fmaf(w1v.w, a[7], acc[n]);
        }
    }
#pragma unroll
    for (int n = 0; n < 8; ++n) {
        acc[n] += __shfl_xor(acc[n], 16);
        acc[n] += __shfl_xor(acc[n], 32);
    }
    if (lane < 16) {
#pragma unroll
        for (int n = 0; n < 8; ++n) lg[e0 + n][rowp] = acc[n];
    }
    __syncthreads();

    // ---- phase 3: softmax + stable top-2 (threads 0..15) ----
    if (t < TR) {
        float l[NE];
#pragma unroll
        for (int e = 0; e < NE; ++e) l[e] = lg[e][t];

        float mx = l[0];
#pragma unroll
        for (int e = 1; e < NE; ++e) mx = fmaxf(mx, l[e]);

        float ssum = 0.f;
#pragma unroll
        for (int e = 0; e < NE; ++e) { float p = expf(l[e] - mx); l[e] = p; ssum += p; }
        const float inv = 1.0f / ssum;
#pragma unroll
        for (int e = 0; e < NE; ++e) l[e] *= inv;

        float v1 = -1.0f, v2 = -2.0f;
        int   i1 = 0,     i2 = 0;
#pragma unroll
        for (int e = 0; e < NE; ++e) {
            const float p  = l[e];
            const bool  g1 = p > v1;
            const bool  g2 = p > v2;
            const float nv2 = g1 ? v1 : (g2 ? p : v2);
            const int   ni2 = g1 ? i1 : (g2 ? e : i2);
            v1 = g1 ? p : v1;
            i1 = g1 ? e : i1;
            v2 = nv2;
            i2 = ni2;
        }

        const int row = r0 + t;
        float* out_idx  = out;
        float* out_gate = out + 2 * NTOK;
        float* out_prob = out + 4 * NTOK;
        out_idx[2 * row + 0]  = (float)i1;
        out_idx[2 * row + 1]  = (float)i2;
        out_gate[2 * row + 0] = v1;
        out_gate[2 * row + 1] = v2;

        float* pr = out_prob + (size_t)row * NE;
#pragma unroll
        for (int e = 0; e < NE; e += 4)
            *(float4*)(pr + e) = make_float4(l[e], l[e + 1], l[e + 2], l[e + 3]);
    }
}

extern "C" void kernel_launch(void* const* d_in, const int* in_sizes, int n_in,
                              void* d_out, int out_size, void* d_ws, size_t ws_size,
                              hipStream_t stream) {
    const float* x  = (const float*)d_in[0];
    const float* w1 = (const float*)d_in[1];
    const float* b1 = (const float*)d_in[2];
    const float* w2 = (const float*)d_in[3];
    float* out = (float*)d_out;

    // workspace: w1t (4 MB) | P (32 MB)  = 36 MB
    unsigned short* w1t = (unsigned short*)d_ws;
    float* P = (float*)((char*)d_ws + (4u << 20));

    convert_w1_kernel<<<512, 512, 0, stream>>>(w1, w1t);
    gemm1_mfma_kernel<<<512, 512, 0, stream>>>(x, w1t, P);
    reduce_gate_kernel<<<512, 512, 0, stream>>>(P, b1, w2, out);
}

// Round 11
// 97.189 us; speedup vs baseline: 1.9167x; 1.3117x over previous
//
#include <hip/hip_runtime.h>
#include <hip/hip_bf16.h>
#include <math.h>

#define NTOK 8192
#define DIN  4096
#define HG   256
#define NE   64
#define SPLITK 4
#define KSTEPS 32          // ksteps of 32 per split (4096/4/32)
#define TR   16            // rows per tail block

typedef __attribute__((ext_vector_type(8))) short short8;
typedef __attribute__((ext_vector_type(4))) short short4v;
typedef __attribute__((ext_vector_type(4))) float f32x4;

__device__ __forceinline__ unsigned short f2bf_rne(float f) {
    union { float f; unsigned int u; } v; v.f = f;
    unsigned int r = v.u + 0x7fffu + ((v.u >> 16) & 1u);
    return (unsigned short)(r >> 16);
}
__device__ __forceinline__ float bf2f(unsigned short b) {
    union { unsigned int u; float f; } v; v.u = ((unsigned int)b) << 16;
    return v.f;
}

typedef const __attribute__((address_space(1))) unsigned int* gptr_t;
typedef __attribute__((address_space(3))) unsigned int* lptr_t;
__device__ __forceinline__ void gload_lds16(const void* g, void* l) {
    __builtin_amdgcn_global_load_lds((gptr_t)g, (lptr_t)l, 16, 0, 0);
}

#define WAIT_VMCNT0 { asm volatile("s_waitcnt vmcnt(0)" ::: "memory"); \
                      __builtin_amdgcn_sched_barrier(0); }
#define WAIT_LGKM0  { asm volatile("s_waitcnt lgkmcnt(0)" ::: "memory"); \
                      __builtin_amdgcn_sched_barrier(0); }

// ---------------------------------------------------------------------------
// Pre-convert w1 [HG][DIN] fp32 -> fragment-ordered bf16 hi/lo tiles.
// w1t[kstep][c][lane][j]: c = hl*16+unit; value = (hi|lo) of
// w1[unit*16 + (lane&15)][kstep*32 + (lane>>4)*8 + j].   (validated r3-r10)
// ---------------------------------------------------------------------------
__global__ __launch_bounds__(512) void convert_w1_kernel(
    const float* __restrict__ w1, unsigned short* __restrict__ w1t)
{
    const int id    = blockIdx.x * 512 + threadIdx.x;
    const int lane  = id & 63;
    const int cg    = id >> 6;           // 0..4095
    const int kstep = cg >> 5;
    const int c     = cg & 31;
    const int hl    = c >> 4;
    const int unit  = c & 15;
    const int n     = unit * 16 + (lane & 15);
    const int k     = kstep * 32 + ((lane >> 4) & 3) * 8;

    const float* src = w1 + (size_t)n * DIN + k;
    short8 v;
#pragma unroll
    for (int j = 0; j < 8; ++j) {
        float f = src[j];
        unsigned short hi = f2bf_rne(f);
        v[j] = (hl == 0) ? (short)hi : (short)f2bf_rne(f - bf2f(hi));
    }
    *(short8*)(w1t + (size_t)cg * 512 + lane * 8) = v;
}

// ---------------------------------------------------------------------------
// GEMM1 (split-K), occupancy-max design:
// P[s][NTOK][HG] = x(bf16x3) @ w1^T for k-range s.
// 1024 blocks = 128 m-tiles (BM=64) x 2 n-tiles (BN=128) x 4 splitK.
// 512 thr = 8 waves (2M x 4N of 32x32 wave tiles; acc = 16 VGPR).
// LDS 40 KB exactly (As single 8 KB + Bs double 32 KB) -> 4 blocks/CU;
// __launch_bounds__(512,8) caps VGPR at 64 -> 8 waves/SIMD, ALL 1024 blocks
// co-resident. Schedule = r6-proven 2-barrier family: B(tt+1) gloads issued
// a full phase before their vmcnt(0); TLP (32 waves/CU) hides the rest.
// ---------------------------------------------------------------------------
__global__ __launch_bounds__(512, 8) void gemm1_mfma_kernel(
    const float* __restrict__ x, const unsigned short* __restrict__ w1t,
    float* __restrict__ P)
{
    __shared__ unsigned short As[2][4][512];     // [hl][unit][slot]  : 8 KB
    __shared__ unsigned short Bs[2][2][8][512];  // [buf][hl][unit][] : 32 KB

    const int bid  = blockIdx.x;
    const int mblk = bid & 127;
    const int nt   = (bid >> 7) & 1;
    const int s    = bid >> 8;
    const int t    = threadIdx.x;
    const int lane = t & 63;
    const int w    = t >> 6;          // 0..7
    const int wm   = w >> 2;          // 0..1
    const int wn   = w & 3;           // 0..3

    const int m_base = mblk * 64;
    const int kstep0 = s * KSTEPS;

    // A staging: thread t -> row = t>>3 (0..63), k4 = (t&7)*4.
    // Per wave: 8 rows x 128 B contiguous (good coalescing).
    const int a_row   = t >> 3;
    const int a_k4    = (t & 7) * 4;
    const int a_unit  = a_row >> 4;
    const int a_off   = (((a_k4 >> 3) << 4) | (a_row & 15)) * 8 + (a_k4 & 7);
    const float* asrc = x + (size_t)(m_base + a_row) * DIN
                          + (size_t)kstep0 * 32 + a_k4;

    f32x4 acc[2][2];
#pragma unroll
    for (int i = 0; i < 2; ++i)
#pragma unroll
        for (int j = 0; j < 2; ++j) acc[i][j] = (f32x4)0.f;

#define CVT4_STORE(F)                                                         \
    {   short4v vh_, vl_;                                                     \
        float ff_[4] = { (F).x, (F).y, (F).z, (F).w };                        \
        _Pragma("unroll")                                                     \
        for (int j_ = 0; j_ < 4; ++j_) {                                      \
            unsigned short h_ = f2bf_rne(ff_[j_]);                            \
            vh_[j_] = (short)h_;                                              \
            vl_[j_] = (short)f2bf_rne(ff_[j_] - bf2f(h_));                    \
        }                                                                     \
        *(short4v*)&As[0][a_unit][a_off] = vh_;                               \
        *(short4v*)&As[1][a_unit][a_off] = vl_;                               \
    }

    // B chunks: 16 x 1KB per kstep (hl*8+unit), 2 per wave.
#define ISSUE_B(KS, BUF)                                                      \
    _Pragma("unroll")                                                         \
    for (int i_ = 0; i_ < 2; ++i_) {                                          \
        const int c_  = w * 2 + i_;                                           \
        const int hl_ = c_ >> 3, un_ = c_ & 7;                                \
        gload_lds16(w1t + ((size_t)(KS) * 32 + hl_ * 16 + nt * 8 + un_) * 512 \
                        + lane * 8,                                           \
                    &Bs[BUF][hl_][un_][0]);                                   \
    }

    // ---- prologue ----
    {
        float4 a0 = *(const float4*)(asrc);
        ISSUE_B(kstep0, 0)
        CVT4_STORE(a0)
        WAIT_VMCNT0
        WAIT_LGKM0
        __builtin_amdgcn_s_barrier();
    }

    int cur = 0;

    // ---- main loop: 2 barriers/kstep, B gloads in flight a full phase ----
#pragma unroll 1
    for (int tt = 0; tt < KSTEPS; ++tt) {
        const bool has1 = (tt + 1 < KSTEPS);

        // issue next-tile loads first (fly across MFMA phase)
        float4 nx;
        if (has1) {
            nx = *(const float4*)(asrc + (size_t)(tt + 1) * 32);
            ISSUE_B(kstep0 + tt + 1, cur ^ 1)
        }

        // A fragments (lane*16B contiguous -> conflict-free)
        short8 ahf[2], alf[2];
#pragma unroll
        for (int mr = 0; mr < 2; ++mr) {
            ahf[mr] = *(const short8*)&As[0][wm * 2 + mr][lane * 8];
            alf[mr] = *(const short8*)&As[1][wm * 2 + mr][lane * 8];
        }

        // per-nr B fragments + bf16x3 (keeps ~24 values live)
        __builtin_amdgcn_s_setprio(1);
#pragma unroll
        for (int nr = 0; nr < 2; ++nr) {
            short8 bh = *(const short8*)&Bs[cur][0][wn * 2 + nr][lane * 8];
            short8 bl = *(const short8*)&Bs[cur][1][wn * 2 + nr][lane * 8];
#pragma unroll
            for (int mr = 0; mr < 2; ++mr)
                acc[mr][nr] = __builtin_amdgcn_mfma_f32_16x16x32_bf16(
                    ahf[mr], bh, acc[mr][nr], 0, 0, 0);
#pragma unroll
            for (int mr = 0; mr < 2; ++mr)
                acc[mr][nr] = __builtin_amdgcn_mfma_f32_16x16x32_bf16(
                    ahf[mr], bl, acc[mr][nr], 0, 0, 0);
#pragma unroll
            for (int mr = 0; mr < 2; ++mr)
                acc[mr][nr] = __builtin_amdgcn_mfma_f32_16x16x32_bf16(
                    alf[mr], bh, acc[mr][nr], 0, 0, 0);
        }
        __builtin_amdgcn_s_setprio(0);

        if (has1) {
            WAIT_LGKM0
            __builtin_amdgcn_s_barrier();   // all waves done reading As

            CVT4_STORE(nx)                  // overwrite As (single buffer)

            WAIT_VMCNT0                     // B(tt+1): issued a phase ago
            WAIT_LGKM0                      // As writes visible
            __builtin_amdgcn_s_barrier();   // tile tt+1 ready
            cur ^= 1;
        }
    }
#undef ISSUE_B
#undef CVT4_STORE

    // ---- epilogue: store fp32 partial (mapping validated r3-r10) ----
    float* pb = P + (size_t)s * ((size_t)NTOK * HG);
#pragma unroll
    for (int mr = 0; mr < 2; ++mr)
#pragma unroll
        for (int nr = 0; nr < 2; ++nr) {
            const int n = nt * 128 + wn * 32 + nr * 16 + (lane & 15);
#pragma unroll
            for (int r = 0; r < 4; ++r) {
                const int m = m_base + wm * 32 + mr * 16 + ((lane >> 4) & 3) * 4 + r;
                pb[(size_t)m * HG + n] = acc[mr][nr][r];
            }
        }
}

// ---------------------------------------------------------------------------
// Fused tail: 512 blocks x 512 thr, TR=16 rows/block, 25 KB LDS ->
// 2 blocks/CU. (unchanged from r6-r10 -- validated, ~4 us)
// d_out = [ indices(float) N*2 | gates N*2 | probs N*64 ]
// ---------------------------------------------------------------------------
__global__ __launch_bounds__(512, 4) void reduce_gate_kernel(
    const float* __restrict__ P, const float* __restrict__ b1,
    const float* __restrict__ w2, float* __restrict__ out)
{
    __shared__ float h_lds[TR][260];
    __shared__ float lg[NE][33];

    const int t    = threadIdx.x;
    const int lane = t & 63;
    const int w    = t >> 6;
    const int r0   = blockIdx.x * TR;
    const size_t SS = (size_t)NTOK * HG;

    // ---- phase 1: reduce + bias + gelu (coalesced: 32 thr = one row) ----
    {
        const int row = t >> 5;          // 0..15
        const int sg  = t & 31;          // 8 floats at cols sg*8
        const size_t base = (size_t)(r0 + row) * HG + sg * 8;

        float q[8];
#pragma unroll
        for (int half = 0; half < 2; ++half) {
            float4 v0 = *(const float4*)(P + base + half * 4);
            float4 v1 = *(const float4*)(P + base + SS + half * 4);
            float4 v2 = *(const float4*)(P + base + 2 * SS + half * 4);
            float4 v3 = *(const float4*)(P + base + 3 * SS + half * 4);
            float4 bb = *(const float4*)(b1 + sg * 8 + half * 4);
            q[half * 4 + 0] = v0.x + v1.x + v2.x + v3.x + bb.x;
            q[half * 4 + 1] = v0.y + v1.y + v2.y + v3.y + bb.y;
            q[half * 4 + 2] = v0.z + v1.z + v2.z + v3.z + bb.z;
            q[half * 4 + 3] = v0.w + v1.w + v2.w + v3.w + bb.w;
        }
#pragma unroll
        for (int c = 0; c < 8; ++c)
            q[c] = 0.5f * q[c] * (1.0f + erff(q[c] * 0.70710678118654752440f));

        *(float4*)&h_lds[row][sg * 8]     = make_float4(q[0], q[1], q[2], q[3]);
        *(float4*)&h_lds[row][sg * 8 + 4] = make_float4(q[4], q[5], q[6], q[7]);
    }
    __syncthreads();

    // ---- phase 2: logits; wave w -> 8 experts, quarter-K per lane ----
    const int e0   = w * 8;
    const int rowp = lane & 15;
    const int kq   = lane >> 4;          // 0..3 -> k-range kq*64

    float acc[8];
#pragma unroll
    for (int i = 0; i < 8; ++i) acc[i] = 0.f;

    const float* w2b = w2 + (size_t)e0 * HG + kq * 64;
#pragma unroll 1
    for (int kc = 0; kc < 64; kc += 8) {
        float a[8];
        *(float4*)&a[0] = *(const float4*)&h_lds[rowp][kq * 64 + kc];
        *(float4*)&a[4] = *(const float4*)&h_lds[rowp][kq * 64 + kc + 4];
#pragma unroll
        for (int n = 0; n < 8; ++n) {
            const float* wr = w2b + (size_t)n * HG + kc;
            float4 w0 = *(const float4*)(wr);
            float4 w1v = *(const float4*)(wr + 4);
            acc[n] = fmaf(w0.x, a[0], acc[n]);
            acc[n] = fmaf(w0.y, a[1], acc[n]);
            acc[n] = fmaf(w0.z, a[2], acc[n]);
            acc[n] = fmaf(w0.w, a[3], acc[n]);
            acc[n] = fmaf(w1v.x, a[4], acc[n]);
            acc[n] = fmaf(w1v.y, a[5], acc[n]);
            acc[n] = fmaf(w1v.z, a[6], acc[n]);
            acc[n] = fmaf(w1v.w, a[7], acc[n]);
        }
    }
#pragma unroll
    for (int n = 0; n < 8; ++n) {
        acc[n] += __shfl_xor(acc[n], 16);
        acc[n] += __shfl_xor(acc[n], 32);
    }
    if (lane < 16) {
#pragma unroll
        for (int n = 0; n < 8; ++n) lg[e0 + n][rowp] = acc[n];
    }
    __syncthreads();

    // ---- phase 3: softmax + stable top-2 (threads 0..15) ----
    if (t < TR) {
        float l[NE];
#pragma unroll
        for (int e = 0; e < NE; ++e) l[e] = lg[e][t];

        float mx = l[0];
#pragma unroll
        for (int e = 1; e < NE; ++e) mx = fmaxf(mx, l[e]);

        float ssum = 0.f;
#pragma unroll
        for (int e = 0; e < NE; ++e) { float p = expf(l[e] - mx); l[e] = p; ssum += p; }
        const float inv = 1.0f / ssum;
#pragma unroll
        for (int e = 0; e < NE; ++e) l[e] *= inv;

        float v1 = -1.0f, v2 = -2.0f;
        int   i1 = 0,     i2 = 0;
#pragma unroll
        for (int e = 0; e < NE; ++e) {
            const float p  = l[e];
            const bool  g1 = p > v1;
            const bool  g2 = p > v2;
            const float nv2 = g1 ? v1 : (g2 ? p : v2);
            const int   ni2 = g1 ? i1 : (g2 ? e : i2);
            v1 = g1 ? p : v1;
            i1 = g1 ? e : i1;
            v2 = nv2;
            i2 = ni2;
        }

        const int row = r0 + t;
        float* out_idx  = out;
        float* out_gate = out + 2 * NTOK;
        float* out_prob = out + 4 * NTOK;
        out_idx[2 * row + 0]  = (float)i1;
        out_idx[2 * row + 1]  = (float)i2;
        out_gate[2 * row + 0] = v1;
        out_gate[2 * row + 1] = v2;

        float* pr = out_prob + (size_t)row * NE;
#pragma unroll
        for (int e = 0; e < NE; e += 4)
            *(float4*)(pr + e) = make_float4(l[e], l[e + 1], l[e + 2], l[e + 3]);
    }
}

extern "C" void kernel_launch(void* const* d_in, const int* in_sizes, int n_in,
                              void* d_out, int out_size, void* d_ws, size_t ws_size,
                              hipStream_t stream) {
    const float* x  = (const float*)d_in[0];
    const float* w1 = (const float*)d_in[1];
    const float* b1 = (const float*)d_in[2];
    const float* w2 = (const float*)d_in[3];
    float* out = (float*)d_out;

    // workspace: w1t (4 MB) | P (32 MB)  = 36 MB
    unsigned short* w1t = (unsigned short*)d_ws;
    float* P = (float*)((char*)d_ws + (4u << 20));

    convert_w1_kernel<<<512, 512, 0, stream>>>(w1, w1t);
    gemm1_mfma_kernel<<<1024, 512, 0, stream>>>(x, w1t, P);
    reduce_gate_kernel<<<512, 512, 0, stream>>>(P, b1, w2, out);
}

// Round 12
// 92.822 us; speedup vs baseline: 2.0069x; 1.0470x over previous
//
#include <hip/hip_runtime.h>
#include <hip/hip_bf16.h>
#include <math.h>

#define NTOK 8192
#define DIN  4096
#define HG   256
#define NE   64
#define SPLITK 4
#define KSTEPS 32          // 32-k tiles per split (4096/4/32)
#define TR   16            // rows per tail block

typedef __attribute__((ext_vector_type(8))) short short8;
typedef __attribute__((ext_vector_type(4))) float f32x4;

__device__ __forceinline__ unsigned short f2bf_rne(float f) {
    union { float f; unsigned int u; } v; v.f = f;
    unsigned int r = v.u + 0x7fffu + ((v.u >> 16) & 1u);
    return (unsigned short)(r >> 16);
}
__device__ __forceinline__ float bf2f(unsigned short b) {
    union { unsigned int u; float f; } v; v.u = ((unsigned int)b) << 16;
    return v.f;
}

typedef const __attribute__((address_space(1))) unsigned int* gptr_t;
typedef __attribute__((address_space(3))) unsigned int* lptr_t;
__device__ __forceinline__ void gload_lds16(const void* g, void* l) {
    __builtin_amdgcn_global_load_lds((gptr_t)g, (lptr_t)l, 16, 0, 0);
}

#define WAIT_VMCNT2 { asm volatile("s_waitcnt vmcnt(2)" ::: "memory"); \
                      __builtin_amdgcn_sched_barrier(0); }
#define WAIT_VMCNT0 { asm volatile("s_waitcnt vmcnt(0)" ::: "memory"); \
                      __builtin_amdgcn_sched_barrier(0); }
#define WAIT_LGKM0  { asm volatile("s_waitcnt lgkmcnt(0)" ::: "memory"); \
                      __builtin_amdgcn_sched_barrier(0); }

// ---------------------------------------------------------------------------
// Pre-convert w1 [HG][DIN] fp32 -> fragment-ordered bf16 hi/lo tiles.
// w1t[kstep][c][lane][j]: c = hl*16+unit; value = (hi|lo) of
// w1[unit*16 + (lane&15)][kstep*32 + (lane>>4)*8 + j].   (validated r3-r11)
// ---------------------------------------------------------------------------
__global__ __launch_bounds__(512) void convert_w1_kernel(
    const float* __restrict__ w1, unsigned short* __restrict__ w1t)
{
    const int id    = blockIdx.x * 512 + threadIdx.x;
    const int lane  = id & 63;
    const int cg    = id >> 6;           // 0..4095
    const int kstep = cg >> 5;
    const int c     = cg & 31;
    const int hl    = c >> 4;
    const int unit  = c & 15;
    const int n     = unit * 16 + (lane & 15);
    const int k     = kstep * 32 + ((lane >> 4) & 3) * 8;

    const float* src = w1 + (size_t)n * DIN + k;
    short8 v;
#pragma unroll
    for (int j = 0; j < 8; ++j) {
        float f = src[j];
        unsigned short hi = f2bf_rne(f);
        v[j] = (hl == 0) ? (short)hi : (short)f2bf_rne(f - bf2f(hi));
    }
    *(short8*)(w1t + (size_t)cg * 512 + lane * 8) = v;
}

// ---------------------------------------------------------------------------
// GEMM1 (split-K), m201-style fine-phase schedule:
// P[s][NTOK][HG] = x(bf16x3) @ w1^T for k-range s.
// 256 blocks = 64 m-tiles (BM=128) x 4 splitK, 1 block/CU; 512 thr = 8 waves
// (2M x 4N of 64x64 wave tiles, 48 MFMA : 16 ds_read = 3:1, fragment-ordered
// LDS -> conflict-free without swizzle). LDS 96 KB: As dbl 32 KB, Bs dbl 64 KB.
// Each 32-K tile = 2 fine phases:
//   PH0: read B frags(8)+A01(4); issue B-gloads(T+1)+x-loads(T+2);
//        barrier; lgkm0; setprio; 24 MFMA(mr0,1); setprio; barrier
//   PH1: read A23(4); CVT x(T+1)->ds_write As[other];
//        barrier; lgkm0; setprio; 24 MFMA(mr2,3); setprio;
//        vmcnt(2) [B(T+1) landed, x(T+2) stays in flight]; barrier
// All addressing/CVT/epilogue byte-identical to r8 (numerically validated).
// ---------------------------------------------------------------------------
__global__ __launch_bounds__(512, 2) void gemm1_mfma_kernel(
    const float* __restrict__ x, const unsigned short* __restrict__ w1t,
    float* __restrict__ P)
{
    __shared__ unsigned short As[2][2][8][512];   // [buf][hl][unit][q*8+j] 32 KB
    __shared__ unsigned short Bs[2][2][16][512];  // [buf][hl][unit][...]   64 KB

    const int bid  = blockIdx.x;
    const int mblk = bid & 63;
    const int s    = bid >> 6;
    const int t    = threadIdx.x;
    const int lane = t & 63;
    const int w    = t >> 6;          // 0..7
    const int wm   = w >> 2;          // 0..1
    const int wn   = w & 3;           // 0..3

    const int m_base = mblk * 128;
    const int kstep0 = s * KSTEPS;

    // A staging (r8 map, conflict-free): thread t -> unit=t>>6, q=t&63,
    // row=unit*16+(q&15), koff=(q>>4)*8; 8 contiguous floats.
    const int a_unit = t >> 6;
    const int a_q    = t & 63;
    const int a_row  = a_unit * 16 + (a_q & 15);
    const int a_koff = (a_q >> 4) * 8;
    const float* asrc = x + (size_t)(m_base + a_row) * DIN
                          + (size_t)kstep0 * 32 + a_koff;
    const int a_ldso = a_q * 8;

    f32x4 acc[4][4];
#pragma unroll
    for (int i = 0; i < 4; ++i)
#pragma unroll
        for (int j = 0; j < 4; ++j) acc[i][j] = (f32x4)0.f;

#define CVT8_STORE(BUF, F0, F1)                                               \
    {   short8 vh_, vl_;                                                      \
        float ff_[8] = { (F0).x, (F0).y, (F0).z, (F0).w,                      \
                         (F1).x, (F1).y, (F1).z, (F1).w };                    \
        _Pragma("unroll")                                                     \
        for (int j_ = 0; j_ < 8; ++j_) {                                      \
            unsigned short h_ = f2bf_rne(ff_[j_]);                            \
            vh_[j_] = (short)h_;                                              \
            vl_[j_] = (short)f2bf_rne(ff_[j_] - bf2f(h_));                    \
        }                                                                     \
        *(short8*)&As[BUF][0][a_unit][a_ldso] = vh_;                          \
        *(short8*)&As[BUF][1][a_unit][a_ldso] = vl_;                          \
    }

#define ISSUE_B(KS, BUF)                                                      \
    _Pragma("unroll")                                                         \
    for (int i_ = 0; i_ < 4; ++i_) {                                          \
        const int c_ = w * 4 + i_;                                            \
        gload_lds16(w1t + ((size_t)(KS) * 32 + c_) * 512 + lane * 8,          \
                    &Bs[BUF][c_ >> 4][c_ & 15][0]);                           \
    }

    // ---- prologue: stage tile 0 fully; preload x for tile 1 ----
    float4 nxc0, nxc1;    // x data consumed by CVT in PH1 (for tile T+1)
    {
        ISSUE_B(kstep0, 0)
        float4 a0 = *(const float4*)(asrc);
        float4 a1 = *(const float4*)(asrc + 4);
        CVT8_STORE(0, a0, a1)            // implicit vmcnt drains B(0) too
        nxc0 = *(const float4*)(asrc + 32);
        nxc1 = *(const float4*)(asrc + 36);
        WAIT_LGKM0
        __builtin_amdgcn_s_barrier();
    }

    int cur = 0;

    // ---- main loop: 2 fine phases per 32-K tile ----
#pragma unroll 1
    for (int tt = 0; tt < KSTEPS; ++tt) {
        const bool has1 = (tt + 1 < KSTEPS);
        const bool has2 = (tt + 2 < KSTEPS);

        // ============ PH0 ============
        // subtile reads: all B frags (kept in regs across PH1) + A mr=0,1
        short8 bh[4], bl[4], ah0, al0, ah1, al1;
#pragma unroll
        for (int nr = 0; nr < 4; ++nr) {
            bh[nr] = *(const short8*)&Bs[cur][0][wn * 4 + nr][lane * 8];
            bl[nr] = *(const short8*)&Bs[cur][1][wn * 4 + nr][lane * 8];
        }
        ah0 = *(const short8*)&As[cur][0][wm * 4 + 0][lane * 8];
        al0 = *(const short8*)&As[cur][1][wm * 4 + 0][lane * 8];
        ah1 = *(const short8*)&As[cur][0][wm * 4 + 1][lane * 8];
        al1 = *(const short8*)&As[cur][1][wm * 4 + 1][lane * 8];

        // stage-issue: B gloads for T+1 FIRST, then x loads for T+2
        if (has1) { ISSUE_B(kstep0 + tt + 1, cur ^ 1) }
        float4 nxn0, nxn1;
        if (has2) {
            const float* ap = asrc + (size_t)(tt + 2) * 32;
            nxn0 = *(const float4*)(ap);
            nxn1 = *(const float4*)(ap + 4);
        }

        __builtin_amdgcn_s_barrier();
        WAIT_LGKM0
        __builtin_amdgcn_s_setprio(1);
#pragma unroll
        for (int nr = 0; nr < 4; ++nr) {
            acc[0][nr] = __builtin_amdgcn_mfma_f32_16x16x32_bf16(ah0, bh[nr], acc[0][nr], 0, 0, 0);
            acc[1][nr] = __builtin_amdgcn_mfma_f32_16x16x32_bf16(ah1, bh[nr], acc[1][nr], 0, 0, 0);
        }
#pragma unroll
        for (int nr = 0; nr < 4; ++nr) {
            acc[0][nr] = __builtin_amdgcn_mfma_f32_16x16x32_bf16(ah0, bl[nr], acc[0][nr], 0, 0, 0);
            acc[1][nr] = __builtin_amdgcn_mfma_f32_16x16x32_bf16(ah1, bl[nr], acc[1][nr], 0, 0, 0);
        }
#pragma unroll
        for (int nr = 0; nr < 4; ++nr) {
            acc[0][nr] = __builtin_amdgcn_mfma_f32_16x16x32_bf16(al0, bh[nr], acc[0][nr], 0, 0, 0);
            acc[1][nr] = __builtin_amdgcn_mfma_f32_16x16x32_bf16(al1, bh[nr], acc[1][nr], 0, 0, 0);
        }
        __builtin_amdgcn_s_setprio(0);
        __builtin_amdgcn_s_barrier();

        // ============ PH1 ============
        short8 ah2, al2, ah3, al3;
        ah2 = *(const short8*)&As[cur][0][wm * 4 + 2][lane * 8];
        al2 = *(const short8*)&As[cur][1][wm * 4 + 2][lane * 8];
        ah3 = *(const short8*)&As[cur][0][wm * 4 + 3][lane * 8];
        al3 = *(const short8*)&As[cur][1][wm * 4 + 3][lane * 8];

        if (has1) { CVT8_STORE(cur ^ 1, nxc0, nxc1) }   // write-late (T14)

        __builtin_amdgcn_s_barrier();
        WAIT_LGKM0
        __builtin_amdgcn_s_setprio(1);
#pragma unroll
        for (int nr = 0; nr < 4; ++nr) {
            acc[2][nr] = __builtin_amdgcn_mfma_f32_16x16x32_bf16(ah2, bh[nr], acc[2][nr], 0, 0, 0);
            acc[3][nr] = __builtin_amdgcn_mfma_f32_16x16x32_bf16(ah3, bh[nr], acc[3][nr], 0, 0, 0);
        }
#pragma unroll
        for (int nr = 0; nr < 4; ++nr) {
            acc[2][nr] = __builtin_amdgcn_mfma_f32_16x16x32_bf16(ah2, bl[nr], acc[2][nr], 0, 0, 0);
            acc[3][nr] = __builtin_amdgcn_mfma_f32_16x16x32_bf16(ah3, bl[nr], acc[3][nr], 0, 0, 0);
        }
#pragma unroll
        for (int nr = 0; nr < 4; ++nr) {
            acc[2][nr] = __builtin_amdgcn_mfma_f32_16x16x32_bf16(al2, bh[nr], acc[2][nr], 0, 0, 0);
            acc[3][nr] = __builtin_amdgcn_mfma_f32_16x16x32_bf16(al3, bh[nr], acc[3][nr], 0, 0, 0);
        }
        __builtin_amdgcn_s_setprio(0);

        if (has1) {
            if (has2) { WAIT_VMCNT2 }    // B(T+1) landed; x(T+2) in flight
            else      { WAIT_VMCNT0 }
        }
        __builtin_amdgcn_s_barrier();    // tile T+1 buffers ready

        nxc0 = nxn0; nxc1 = nxn1;
        cur ^= 1;
    }
#undef ISSUE_B
#undef CVT8_STORE

    // ---- epilogue: store fp32 partial (mapping validated r3-r11) ----
    float* pb = P + (size_t)s * ((size_t)NTOK * HG);
#pragma unroll
    for (int mr = 0; mr < 4; ++mr)
#pragma unroll
        for (int nr = 0; nr < 4; ++nr) {
            const int n = wn * 64 + nr * 16 + (lane & 15);
#pragma unroll
            for (int r = 0; r < 4; ++r) {
                const int m = m_base + wm * 64 + mr * 16 + ((lane >> 4) & 3) * 4 + r;
                pb[(size_t)m * HG + n] = acc[mr][nr][r];
            }
        }
}

// ---------------------------------------------------------------------------
// Fused tail: 512 blocks x 512 thr, TR=16 rows/block, 25 KB LDS ->
// 2 blocks/CU. (unchanged from r6-r11 -- validated, ~4 us)
// d_out = [ indices(float) N*2 | gates N*2 | probs N*64 ]
// ---------------------------------------------------------------------------
__global__ __launch_bounds__(512, 4) void reduce_gate_kernel(
    const float* __restrict__ P, const float* __restrict__ b1,
    const float* __restrict__ w2, float* __restrict__ out)
{
    __shared__ float h_lds[TR][260];
    __shared__ float lg[NE][33];

    const int t    = threadIdx.x;
    const int lane = t & 63;
    const int w    = t >> 6;
    const int r0   = blockIdx.x * TR;
    const size_t SS = (size_t)NTOK * HG;

    // ---- phase 1: reduce + bias + gelu (coalesced: 32 thr = one row) ----
    {
        const int row = t >> 5;          // 0..15
        const int sg  = t & 31;          // 8 floats at cols sg*8
        const size_t base = (size_t)(r0 + row) * HG + sg * 8;

        float q[8];
#pragma unroll
        for (int half = 0; half < 2; ++half) {
            float4 v0 = *(const float4*)(P + base + half * 4);
            float4 v1 = *(const float4*)(P + base + SS + half * 4);
            float4 v2 = *(const float4*)(P + base + 2 * SS + half * 4);
            float4 v3 = *(const float4*)(P + base + 3 * SS + half * 4);
            float4 bb = *(const float4*)(b1 + sg * 8 + half * 4);
            q[half * 4 + 0] = v0.x + v1.x + v2.x + v3.x + bb.x;
            q[half * 4 + 1] = v0.y + v1.y + v2.y + v3.y + bb.y;
            q[half * 4 + 2] = v0.z + v1.z + v2.z + v3.z + bb.z;
            q[half * 4 + 3] = v0.w + v1.w + v2.w + v3.w + bb.w;
        }
#pragma unroll
        for (int c = 0; c < 8; ++c)
            q[c] = 0.5f * q[c] * (1.0f + erff(q[c] * 0.70710678118654752440f));

        *(float4*)&h_lds[row][sg * 8]     = make_float4(q[0], q[1], q[2], q[3]);
        *(float4*)&h_lds[row][sg * 8 + 4] = make_float4(q[4], q[5], q[6], q[7]);
    }
    __syncthreads();

    // ---- phase 2: logits; wave w -> 8 experts, quarter-K per lane ----
    const int e0   = w * 8;
    const int rowp = lane & 15;
    const int kq   = lane >> 4;          // 0..3 -> k-range kq*64

    float acc[8];
#pragma unroll
    for (int i = 0; i < 8; ++i) acc[i] = 0.f;

    const float* w2b = w2 + (size_t)e0 * HG + kq * 64;
#pragma unroll 1
    for (int kc = 0; kc < 64; kc += 8) {
        float a[8];
        *(float4*)&a[0] = *(const float4*)&h_lds[rowp][kq * 64 + kc];
        *(float4*)&a[4] = *(const float4*)&h_lds[rowp][kq * 64 + kc + 4];
#pragma unroll
        for (int n = 0; n < 8; ++n) {
            const float* wr = w2b + (size_t)n * HG + kc;
            float4 w0 = *(const float4*)(wr);
            float4 w1v = *(const float4*)(wr + 4);
            acc[n] = fmaf(w0.x, a[0], acc[n]);
            acc[n] = fmaf(w0.y, a[1], acc[n]);
            acc[n] = fmaf(w0.z, a[2], acc[n]);
            acc[n] = fmaf(w0.w, a[3], acc[n]);
            acc[n] = fmaf(w1v.x, a[4], acc[n]);
            acc[n] = fmaf(w1v.y, a[5], acc[n]);
            acc[n] = fmaf(w1v.z, a[6], acc[n]);
            acc[n] = fmaf(w1v.w, a[7], acc[n]);
        }
    }
#pragma unroll
    for (int n = 0; n < 8; ++n) {
        acc[n] += __shfl_xor(acc[n], 16);
        acc[n] += __shfl_xor(acc[n], 32);
    }
    if (lane < 16) {
#pragma unroll
        for (int n = 0; n < 8; ++n) lg[e0 + n][rowp] = acc[n];
    }
    __syncthreads();

    // ---- phase 3: softmax + stable top-2 (threads 0..15) ----
    if (t < TR) {
        float l[NE];
#pragma unroll
        for (int e = 0; e < NE; ++e) l[e] = lg[e][t];

        float mx = l[0];
#pragma unroll
        for (int e = 1; e < NE; ++e) mx = fmaxf(mx, l[e]);

        float ssum = 0.f;
#pragma unroll
        for (int e = 0; e < NE; ++e) { float p = expf(l[e] - mx); l[e] = p; ssum += p; }
        const float inv = 1.0f / ssum;
#pragma unroll
        for (int e = 0; e < NE; ++e) l[e] *= inv;

        float v1 = -1.0f, v2 = -2.0f;
        int   i1 = 0,     i2 = 0;
#pragma unroll
        for (int e = 0; e < NE; ++e) {
            const float p  = l[e];
            const bool  g1 = p > v1;
            const bool  g2 = p > v2;
            const float nv2 = g1 ? v1 : (g2 ? p : v2);
            const int   ni2 = g1 ? i1 : (g2 ? e : i2);
            v1 = g1 ? p : v1;
            i1 = g1 ? e : i1;
            v2 = nv2;
            i2 = ni2;
        }

        const int row = r0 + t;
        float* out_idx  = out;
        float* out_gate = out + 2 * NTOK;
        float* out_prob = out + 4 * NTOK;
        out_idx[2 * row + 0]  = (float)i1;
        out_idx[2 * row + 1]  = (float)i2;
        out_gate[2 * row + 0] = v1;
        out_gate[2 * row + 1] = v2;

        float* pr = out_prob + (size_t)row * NE;
#pragma unroll
        for (int e = 0; e < NE; e += 4)
            *(float4*)(pr + e) = make_float4(l[e], l[e + 1], l[e + 2], l[e + 3]);
    }
}

extern "C" void kernel_launch(void* const* d_in, const int* in_sizes, int n_in,
                              void* d_out, int out_size, void* d_ws, size_t ws_size,
                              hipStream_t stream) {
    const float* x  = (const float*)d_in[0];
    const float* w1 = (const float*)d_in[1];
    const float* b1 = (const float*)d_in[2];
    const float* w2 = (const float*)d_in[3];
    float* out = (float*)d_out;

    // workspace: w1t (4 MB) | P (32 MB)  = 36 MB
    unsigned short* w1t = (unsigned short*)d_ws;
    float* P = (float*)((char*)d_ws + (4u << 20));

    convert_w1_kernel<<<512, 512, 0, stream>>>(w1, w1t);
    gemm1_mfma_kernel<<<256, 512, 0, stream>>>(x, w1t, P);
    reduce_gate_kernel<<<512, 512, 0, stream>>>(P, b1, w2, out);
}